// Round 4
// baseline (346.078 us; speedup 1.0000x reference)
//
#include <hip/hip_runtime.h>
#include <hip/hip_bf16.h>

typedef __attribute__((ext_vector_type(8))) short short8;
typedef __attribute__((ext_vector_type(4))) float f32x4;
typedef __attribute__((ext_vector_type(2))) unsigned int u32x2;

#define S_LEN 2048
#define D_DIM 128
#define BM 128     // q rows per block (8 waves x 16 rows)
#define BN 64      // kv rows per tile
#define NW 8
#define PST 72     // P lds row stride (shorts)
#define KSWZ(r) (((r) & 7) << 4)          // K row XOR swizzle (16B granular)
#define VSWZ(d) ((((d) >> 1) & 7) << 4)   // Vt row XOR swizzle

__device__ __forceinline__ unsigned short bfbits(float f) {
  return __builtin_bit_cast(unsigned short, __float2bfloat16(f));
}
__device__ __forceinline__ unsigned int pk2(float lo, float hi) {
  return (unsigned int)bfbits(lo) | ((unsigned int)bfbits(hi) << 16);
}
__device__ __forceinline__ short f2bf(float f) {
  return __builtin_bit_cast(short, __float2bfloat16(f));
}

extern "C" __global__ void __launch_bounds__(512, 4)
fa_fwd_kernel(const float* __restrict__ Qg, const float* __restrict__ Kg,
              const float* __restrict__ Vg, float* __restrict__ Og)
{
  // LDS: K double-buffered swizzled (2 x 64 rows x 256B = 32768)
  //      Vt single-buffered swizzled (128 rows x 128B = 16384)
  //      P  per-wave (8 x 16 x 72 shorts = 18432)   total 67584 -> 2 blocks/CU
  __shared__ __align__(16) char smem[67584];
  char*  Ksh = smem;
  char*  Vsh = smem + 32768;
  short* Psh = (short*)(smem + 49152);

  const int bh = blockIdx.x;                        // XCD = bh%8 -> K/V L2 locality
  const int qt = 15 - (int)blockIdx.y;              // heavy q-tiles dispatch first
  const int m0 = qt * BM;
  const int tid = threadIdx.x;
  const int wv  = tid >> 6;
  const int ln  = tid & 63;
  const int l15 = ln & 15;
  const int lhi = ln >> 4;
  const int vg  = tid & 31;   // V staging: d-group
  const int vp  = tid >> 5;   // V staging: kv quad 0..15

  const size_t base = (size_t)bh * S_LEN * D_DIM;
  const float* Qb = Qg + base;
  const float* Kb = Kg + base;
  const float* Vb = Vg + base;
  float*       Ob = Og + base;

  const float scale = 0.08838834764831845f; // 1/sqrt(128)
  const int wrow_lo = m0 + wv * 16;
  short* pw = &Psh[wv * 16 * PST];

  // ---- Q fragments in registers (bf16, pre-scaled) ----
  short8 qf[4];
  {
    const float* qsrc = Qb + (size_t)(wrow_lo + l15) * D_DIM + lhi * 8;
    #pragma unroll
    for (int kk = 0; kk < 4; ++kk) {
      f32x4 a = *(const f32x4*)(qsrc + kk * 32);
      f32x4 b = *(const f32x4*)(qsrc + kk * 32 + 4);
      short8 f;
      f[0] = f2bf(a[0] * scale); f[1] = f2bf(a[1] * scale);
      f[2] = f2bf(a[2] * scale); f[3] = f2bf(a[3] * scale);
      f[4] = f2bf(b[0] * scale); f[5] = f2bf(b[1] * scale);
      f[6] = f2bf(b[2] * scale); f[7] = f2bf(b[3] * scale);
      qf[kk] = f;
    }
  }

  // ---- staging helpers ----
  auto load_k = [&](int t, f32x4* kr) {
    const float* Kt = Kb + (size_t)t * BN * D_DIM;
    #pragma unroll
    for (int i = 0; i < 4; ++i) {
      int idx = i * 512 + tid;
      kr[i] = *(const f32x4*)(Kt + (size_t)(idx >> 5) * D_DIM + (idx & 31) * 4);
    }
  };
  auto store_k = [&](char* kb, const f32x4* kr) {
    #pragma unroll
    for (int i = 0; i < 4; ++i) {
      int idx = i * 512 + tid;
      int row = idx >> 5, c = idx & 31;   // 8B chunk per thread, rows contiguous
      u32x2 w; w[0] = pk2(kr[i][0], kr[i][1]); w[1] = pk2(kr[i][2], kr[i][3]);
      *(u32x2*)(kb + ((row * 256 + c * 8) ^ KSWZ(row))) = w;
    }
  };
  auto load_v = [&](int t, f32x4* vr) {
    const float* Vt = Vb + (size_t)t * BN * D_DIM;
    #pragma unroll
    for (int r = 0; r < 4; ++r)
      vr[r] = *(const f32x4*)(Vt + (size_t)(4 * vp + r) * D_DIM + vg * 4);
  };
  auto store_v = [&](const f32x4* vr) {
    #pragma unroll
    for (int j = 0; j < 4; ++j) {
      int d = vg * 4 + j;
      u32x2 w; w[0] = pk2(vr[0][j], vr[1][j]); w[1] = pk2(vr[2][j], vr[3][j]);
      *(u32x2*)(Vsh + ((d * 128 + vp * 8) ^ VSWZ(d))) = w;  // kv 4vp..4vp+3 of dim d
    }
  };

  const f32x4 fzero = {0.f, 0.f, 0.f, 0.f};
  f32x4 oacc[8];
  #pragma unroll
  for (int i = 0; i < 8; ++i) oacc[i] = fzero;
  float mrow[4] = {-INFINITY, -INFINITY, -INFINITY, -INFINITY};
  float lrow[4] = {0.f, 0.f, 0.f, 0.f};

  const int ntiles = 2 * qt + 2;

  // ---- prologue: stage tile 0 ----
  {
    f32x4 kr[4], vr[4];
    load_k(0, kr); load_v(0, vr);
    store_k(Ksh, kr); store_v(vr);
  }
  __syncthreads();

  int cur = 0;
  for (int t = 0; t < ntiles; ++t) {
    const int kv0 = t * BN;
    const bool pf = (t + 1 < ntiles);
    const bool comp = (kv0 <= wrow_lo + 15);   // wave-uniform causal skip

    f32x4 kr[4], vr[4];
    if (pf) { load_k(t + 1, kr); load_v(t + 1, vr); }   // issue early

    f32x4 sacc[4];
    if (comp) {
      // ---- S = (Q*scale) K^T ----
      const char* Kl = Ksh + cur * 16384;
      __builtin_amdgcn_s_setprio(1);
      #pragma unroll
      for (int nc = 0; nc < 4; ++nc) {
        sacc[nc] = fzero;
        #pragma unroll
        for (int kk = 0; kk < 4; ++kk) {
          int krow = nc * 16 + l15;
          short8 kf = *(const short8*)(Kl + ((krow * 256 + kk * 64 + lhi * 16) ^ KSWZ(krow)));
          sacc[nc] = __builtin_amdgcn_mfma_f32_16x16x32_bf16(qf[kk], kf, sacc[nc], 0, 0, 0);
        }
      }
      __builtin_amdgcn_s_setprio(0);
    }

    if (pf) store_k(Ksh + (cur ^ 1) * 16384, kr);  // K(t+1) to alt buf: safe pre-barrier

    if (comp) {
      // ---- causal mask (diagonal tile only for this wave) ----
      if (kv0 + BN - 1 > wrow_lo) {
        #pragma unroll
        for (int nc = 0; nc < 4; ++nc)
          #pragma unroll
          for (int r = 0; r < 4; ++r) {
            int kcol = kv0 + nc * 16 + l15;
            int qrow = wrow_lo + lhi * 4 + r;
            if (kcol > qrow) sacc[nc][r] = -INFINITY;
          }
      }

      // ---- online softmax ----
      float pmax[4] = {-INFINITY, -INFINITY, -INFINITY, -INFINITY};
      #pragma unroll
      for (int nc = 0; nc < 4; ++nc)
        #pragma unroll
        for (int r = 0; r < 4; ++r) pmax[r] = fmaxf(pmax[r], sacc[nc][r]);
      #pragma unroll
      for (int off = 1; off < 16; off <<= 1)
        #pragma unroll
        for (int r = 0; r < 4; ++r)
          pmax[r] = fmaxf(pmax[r], __shfl_xor(pmax[r], off));

      float alpha[4];
      #pragma unroll
      for (int r = 0; r < 4; ++r) {
        float mn = fmaxf(mrow[r], pmax[r]);
        alpha[r] = __expf(mrow[r] - mn);
        mrow[r] = mn;
      }

      float rsum[4] = {0.f, 0.f, 0.f, 0.f};
      #pragma unroll
      for (int nc = 0; nc < 4; ++nc)
        #pragma unroll
        for (int r = 0; r < 4; ++r) {
          float p = __expf(sacc[nc][r] - mrow[r]);
          sacc[nc][r] = p;
          rsum[r] += p;
        }
      #pragma unroll
      for (int off = 1; off < 16; off <<= 1)
        #pragma unroll
        for (int r = 0; r < 4; ++r)
          rsum[r] += __shfl_xor(rsum[r], off);

      #pragma unroll
      for (int r = 0; r < 4; ++r) lrow[r] = lrow[r] * alpha[r] + rsum[r];
      #pragma unroll
      for (int dc = 0; dc < 8; ++dc)
        #pragma unroll
        for (int r = 0; r < 4; ++r) oacc[dc][r] *= alpha[r];

      // ---- P (C-layout) -> per-wave LDS (wave-local, no barrier) ----
      #pragma unroll
      for (int nc = 0; nc < 4; ++nc)
        #pragma unroll
        for (int r = 0; r < 4; ++r)
          pw[(lhi * 4 + r) * PST + nc * 16 + l15] = f2bf(sacc[nc][r]);

      // ---- O += P V ----
      __builtin_amdgcn_s_setprio(1);
      #pragma unroll
      for (int kk = 0; kk < 2; ++kk) {
        short8 pfr = *(const short8*)&pw[l15 * PST + kk * 32 + lhi * 8];
        #pragma unroll
        for (int dc = 0; dc < 8; ++dc) {
          int d = dc * 16 + l15;
          short8 vf = *(const short8*)(Vsh + ((d * 128 + kk * 64 + lhi * 16) ^ VSWZ(d)));
          oacc[dc] = __builtin_amdgcn_mfma_f32_16x16x32_bf16(pfr, vf, oacc[dc], 0, 0, 0);
        }
      }
      __builtin_amdgcn_s_setprio(0);
    }

    __syncthreads();               // all waves done reading Vcur (and Kcur)
    if (pf) store_v(vr);           // V(t+1) into the single V buffer
    __syncthreads();               // V(t+1) visible to all
    cur ^= 1;
  }

  // ---- epilogue: O / l ----
  float inv[4];
  #pragma unroll
  for (int r = 0; r < 4; ++r) inv[r] = 1.0f / lrow[r];
  #pragma unroll
  for (int dc = 0; dc < 8; ++dc)
    #pragma unroll
    for (int r = 0; r < 4; ++r)
      Ob[(size_t)(wrow_lo + lhi * 4 + r) * D_DIM + dc * 16 + l15] =
          oacc[dc][r] * inv[r];
}

extern "C" void kernel_launch(void* const* d_in, const int* in_sizes, int n_in,
                              void* d_out, int out_size, void* d_ws, size_t ws_size,
                              hipStream_t stream) {
  const float* Q = (const float*)d_in[0];
  const float* K = (const float*)d_in[1];
  const float* V = (const float*)d_in[2];
  float* O = (float*)d_out;
  dim3 grid(32 /* B*H */, S_LEN / BM);
  dim3 block(512);
  fa_fwd_kernel<<<grid, block, 0, stream>>>(Q, K, V, O);
}

// Round 5
// 113.832 us; speedup vs baseline: 3.0403x; 3.0403x over previous
//
#include <hip/hip_runtime.h>
#include <hip/hip_bf16.h>

typedef __attribute__((ext_vector_type(8))) short short8;
typedef __attribute__((ext_vector_type(4))) float f32x4;
typedef __attribute__((ext_vector_type(4))) unsigned int u32x4;
typedef __attribute__((ext_vector_type(2))) unsigned int u32x2;

#define S_LEN 2048
#define D_DIM 128
#define BM 128        // q rows per block (8 waves x 16)
#define BN 64         // kv rows per tile
#define KSTb 272      // K lds row stride bytes (128 bf16 + 8 pad) - read conflict-free
#define VSTb 144      // Vt lds row stride bytes (64 bf16 + 8 pad)
#define KBUF 17408    // 64*272
#define VBUF 18432    // 128*144

__device__ __forceinline__ unsigned short bfbits(float f) {
  return __builtin_bit_cast(unsigned short, __float2bfloat16(f));
}
__device__ __forceinline__ unsigned int pk2(float lo, float hi) {
  return (unsigned int)bfbits(lo) | ((unsigned int)bfbits(hi) << 16);
}
__device__ __forceinline__ short f2bf(float f) {
  return __builtin_bit_cast(short, __float2bfloat16(f));
}

extern "C" __global__ void __launch_bounds__(512, 4)
fa_fwd_kernel(const float* __restrict__ Qg, const float* __restrict__ Kg,
              const float* __restrict__ Vg, float* __restrict__ Og)
{
  // LDS: K double-buffered 34816 + Vt double-buffered 36864 = 71680 (2 blocks/CU)
  // Epilogue reuses smem as [128][130] f32 transpose buffer (66560 B).
  __shared__ __align__(16) char smem[71680];
  char* Ksh = smem;
  char* Vsh = smem + 2 * KBUF;
  float* Osh = (float*)smem;

  const int bh = blockIdx.x;                   // XCD = bh%8 -> K/V L2 locality
  const int qt = 15 - (int)blockIdx.y;         // heavy q-tiles dispatch first
  const int m0 = qt * BM;
  const int tid = threadIdx.x;
  const int wv  = tid >> 6;
  const int ln  = tid & 63;
  const int l15 = ln & 15;
  const int lhi = ln >> 4;

  const size_t base = (size_t)bh * S_LEN * D_DIM;
  const float* Qb = Qg + base;
  const float* Kb = Kg + base;
  const float* Vb = Vg + base;
  float*       Ob = Og + base;

  const float scale = 0.08838834764831845f;    // 1/sqrt(128)
  const int wrow_lo = m0 + wv * 16;
  const int qg = wrow_lo + l15;                // this lane's q row (swapped layout)
  // QK A-read row permutation so lane's S values match PV B-frag kv's:
  // sigma(c,m) = 8*(m>>2) + (m&3) + 4*(c&1) + 32*(c>>1), read with m=l15
  const int arow = ((l15 >> 2) << 3) + (l15 & 3);

  // ---- Q B-frags (bf16, pre-scaled): lane holds q=l15, k=d=lhi*8+j ----
  short8 qf[4];
  {
    const float* qsrc = Qb + (size_t)(wrow_lo + l15) * D_DIM + lhi * 8;
    #pragma unroll
    for (int kk = 0; kk < 4; ++kk) {
      f32x4 a = *(const f32x4*)(qsrc + kk * 32);
      f32x4 b = *(const f32x4*)(qsrc + kk * 32 + 4);
      short8 f;
      f[0] = f2bf(a[0] * scale); f[1] = f2bf(a[1] * scale);
      f[2] = f2bf(a[2] * scale); f[3] = f2bf(a[3] * scale);
      f[4] = f2bf(b[0] * scale); f[5] = f2bf(b[1] * scale);
      f[6] = f2bf(b[2] * scale); f[7] = f2bf(b[3] * scale);
      qf[kk] = f;
    }
  }

  // ---- staging helpers (512 threads) ----
  auto load_k = [&](int t, f32x4* kr) {
    const float* Kt = Kb + (size_t)t * BN * D_DIM;
    #pragma unroll
    for (int i = 0; i < 4; ++i) {
      int idx = i * 512 + tid;
      kr[i] = *(const f32x4*)(Kt + (size_t)(idx >> 5) * D_DIM + (idx & 31) * 4);
    }
  };
  auto store_k = [&](char* kb, const f32x4* kr) {
    #pragma unroll
    for (int i = 0; i < 4; ++i) {
      int idx = i * 512 + tid;
      u32x2 w; w[0] = pk2(kr[i][0], kr[i][1]); w[1] = pk2(kr[i][2], kr[i][3]);
      *(u32x2*)(kb + (idx >> 5) * KSTb + (idx & 31) * 8) = w;
    }
  };
  auto load_v = [&](int t, f32x4* vr) {
    const float* Vt = Vb + (size_t)t * BN * D_DIM;
    #pragma unroll
    for (int i = 0; i < 4; ++i) {
      int idx = i * 512 + tid;
      vr[i] = *(const f32x4*)(Vt + (size_t)(idx & 63) * D_DIM + (idx >> 6) * 4);
    }
  };
  auto store_v = [&](char* vb, const f32x4* vr) {
    #pragma unroll
    for (int i = 0; i < 4; ++i) {
      int idx = i * 512 + tid;
      int vrow = idx & 63, vc4 = idx >> 6;
      #pragma unroll
      for (int j = 0; j < 4; ++j)   // Vt[d][kv]: bank = lane/2 -> 2-way, free
        *(short*)(vb + (vc4 * 4 + j) * VSTb + vrow * 2) = f2bf(vr[i][j]);
    }
  };

  const f32x4 fzero = {0.f, 0.f, 0.f, 0.f};
  f32x4 oacc[8];                                // O^T: lane holds col q=l15
  #pragma unroll
  for (int i = 0; i < 8; ++i) oacc[i] = fzero;
  float m_run = -INFINITY, l_run = 0.f;

  const int ntiles = 2 * qt + 2;

  // ---- prologue: stage tile 0 into buf 0 ----
  {
    f32x4 st[4];
    load_k(0, st); store_k(Ksh, st);
    load_v(0, st); store_v(Vsh, st);
  }
  __syncthreads();

  int cur = 0;
  for (int t = 0; t < ntiles; ++t) {
    const int kv0 = t * BN;
    const bool pf = (t + 1 < ntiles);
    const bool comp = (kv0 <= wrow_lo + 15);    // wave-uniform causal skip

    f32x4 st[4];
    if (pf) load_k(t + 1, st);                  // issue early, hide under QK

    f32x4 sacc[4];
    if (comp) {
      // ---- S^T = K Q^T : A=K(perm rows), B=Q; lane -> q=l15, kv in-reg ----
      const char* Kl = Ksh + cur * KBUF;
      __builtin_amdgcn_s_setprio(1);
      #pragma unroll
      for (int c = 0; c < 4; ++c) {
        sacc[c] = fzero;
        const int krow = arow + (c & 1) * 4 + (c >> 1) * 32;
        #pragma unroll
        for (int kk = 0; kk < 4; ++kk) {
          short8 kf = *(const short8*)(Kl + krow * KSTb + kk * 64 + lhi * 16);
          sacc[c] = __builtin_amdgcn_mfma_f32_16x16x32_bf16(kf, qf[kk], sacc[c], 0, 0, 0);
        }
      }
      __builtin_amdgcn_s_setprio(0);
    }

    if (pf) store_k(Ksh + (cur ^ 1) * KBUF, st);  // K(t+1) -> alt buf
    if (pf) load_v(t + 1, st);                     // reuse regs; hides under softmax/PV

    if (comp) {
      // ---- causal mask: sacc[c][r] is kv = kv0 + 32(c>>1)+4(c&1)+8*lhi+r ----
      if (kv0 + BN - 1 > wrow_lo) {
        #pragma unroll
        for (int c = 0; c < 4; ++c) {
          const int kvb = kv0 + (c >> 1) * 32 + (c & 1) * 4 + lhi * 8;
          #pragma unroll
          for (int r = 0; r < 4; ++r)
            if (kvb + r > qg) sacc[c][r] = -INFINITY;
        }
      }

      // ---- online softmax: fully per-lane (own q row) + 2 shfls ----
      float mt = -INFINITY;
      #pragma unroll
      for (int c = 0; c < 4; ++c)
        #pragma unroll
        for (int r = 0; r < 4; ++r) mt = fmaxf(mt, sacc[c][r]);
      mt = fmaxf(mt, __shfl_xor(mt, 16));
      mt = fmaxf(mt, __shfl_xor(mt, 32));
      const float m_new = fmaxf(m_run, mt);
      const float alpha = __expf(m_run - m_new);
      m_run = m_new;

      float rs = 0.f;
      #pragma unroll
      for (int c = 0; c < 4; ++c)
        #pragma unroll
        for (int r = 0; r < 4; ++r) {
          float p = __expf(sacc[c][r] - m_new);
          sacc[c][r] = p;
          rs += p;
        }
      rs += __shfl_xor(rs, 16);
      rs += __shfl_xor(rs, 32);
      l_run = l_run * alpha + rs;

      #pragma unroll
      for (int dc = 0; dc < 8; ++dc)
        #pragma unroll
        for (int r = 0; r < 4; ++r) oacc[dc][r] *= alpha;

      // ---- P^T B-frags: pure in-lane packing (kv = 8*lhi+j by construction) ----
      short8 pfrag[2];
      #pragma unroll
      for (int w = 0; w < 2; ++w) {
        u32x4 u;
        u[0] = pk2(sacc[2 * w][0], sacc[2 * w][1]);
        u[1] = pk2(sacc[2 * w][2], sacc[2 * w][3]);
        u[2] = pk2(sacc[2 * w + 1][0], sacc[2 * w + 1][1]);
        u[3] = pk2(sacc[2 * w + 1][2], sacc[2 * w + 1][3]);
        pfrag[w] = __builtin_bit_cast(short8, u);
      }

      // ---- O^T += V^T P^T : A=V^T (lane d=l15), B=P^T (lane q=l15) ----
      const char* Vl = Vsh + cur * VBUF;
      __builtin_amdgcn_s_setprio(1);
      #pragma unroll
      for (int dc = 0; dc < 8; ++dc) {
        const int drow = dc * 16 + l15;
        #pragma unroll
        for (int w = 0; w < 2; ++w) {
          short8 vf = *(const short8*)(Vl + drow * VSTb + w * 64 + lhi * 16);
          oacc[dc] = __builtin_amdgcn_mfma_f32_16x16x32_bf16(vf, pfrag[w], oacc[dc], 0, 0, 0);
        }
      }
      __builtin_amdgcn_s_setprio(0);
    }

    if (pf) store_v(Vsh + (cur ^ 1) * VBUF, st);   // V(t+1) -> alt buf
    __syncthreads();                               // alt bufs ready; cur reads done
    cur ^= 1;
  }

  // ---- epilogue: O^T/l -> LDS transpose -> coalesced f32x4 stores ----
  __syncthreads();   // everyone past last reads of K/V lds before overwrite
  const float invl = 1.0f / l_run;
  #pragma unroll
  for (int dc = 0; dc < 8; ++dc)
    #pragma unroll
    for (int r = 0; r < 4; ++r) {
      const int d = dc * 16 + lhi * 4 + r;        // C row -> d
      Osh[(wv * 16 + l15) * 130 + d] = oacc[dc][r] * invl;
    }
  __syncthreads();
  #pragma unroll
  for (int i = 0; i < 8; ++i) {
    int idx = i * 512 + tid;
    int row = idx >> 5, c4 = idx & 31;
    f32x4 v = *(const f32x4*)&Osh[row * 130 + c4 * 4];
    *(f32x4*)(Ob + (size_t)(m0 + row) * D_DIM + c4 * 4) = v;
  }
}

extern "C" void kernel_launch(void* const* d_in, const int* in_sizes, int n_in,
                              void* d_out, int out_size, void* d_ws, size_t ws_size,
                              hipStream_t stream) {
  const float* Q = (const float*)d_in[0];
  const float* K = (const float*)d_in[1];
  const float* V = (const float*)d_in[2];
  float* O = (float*)d_out;
  dim3 grid(32 /* B*H */, S_LEN / BM);
  dim3 block(512);
  fa_fwd_kernel<<<grid, block, 0, stream>>>(Q, K, V, O);
}

// Round 6
// 89.113 us; speedup vs baseline: 3.8836x; 1.2774x over previous
//
#include <hip/hip_runtime.h>
#include <hip/hip_bf16.h>

typedef __attribute__((ext_vector_type(8))) short short8;
typedef __attribute__((ext_vector_type(4))) float f32x4;
typedef __attribute__((ext_vector_type(4))) unsigned int u32x4;
typedef __attribute__((ext_vector_type(2))) unsigned int u32x2;

#define S_LEN 2048
#define D_DIM 128
#define BM 128        // q rows per block (8 waves x 16)
#define BN 64         // kv rows per tile
#define KBUF 16384    // 64 rows x 256B, XOR-swizzled
#define VBUF 16384    // 128 rows x 128B (transposed), XOR-swizzled

__device__ __forceinline__ unsigned short bfbits(float f) {
  return __builtin_bit_cast(unsigned short, __float2bfloat16(f));
}
__device__ __forceinline__ unsigned int pk2(float lo, float hi) {
  return (unsigned int)bfbits(lo) | ((unsigned int)bfbits(hi) << 16);
}
__device__ __forceinline__ float exp2f_hw(float x) {   // exp2; handles -inf -> 0
  float r;
  asm("v_exp_f32 %0, %1" : "=v"(r) : "v"(x));
  return r;
}

extern "C" __global__ void __launch_bounds__(512, 4)
fa_fwd_kernel(const float* __restrict__ Qg, const float* __restrict__ Kg,
              const float* __restrict__ Vg, float* __restrict__ Og)
{
  __shared__ __align__(16) char smem[65536];   // exactly 64KB -> 2 blocks/CU
  char* Ksh = smem;                // [2][KBUF]
  char* Vsh = smem + 2 * KBUF;     // [2][VBUF]
  float* Osh = (float*)smem;       // epilogue reuse: [64][132] f32

  const int bh = blockIdx.x;                   // XCD = bh%8 -> K/V L2 locality
  const int qt = 15 - (int)blockIdx.y;         // heavy q-tiles dispatch first
  const int m0 = qt * BM;
  const int tid = threadIdx.x;
  const int wv  = tid >> 6;
  const int ln  = tid & 63;
  const int l15 = ln & 15;
  const int lhi = ln >> 4;          // 0..3 (k-slice of MFMA fragment)
  const int vg4 = (tid & 31) * 4;   // V staging: first d of this thread
  const int vp  = tid >> 5;         // V staging: kv quad index 0..15

  const size_t base = (size_t)bh * S_LEN * D_DIM;
  const float* Qb = Qg + base;
  const float* Kb = Kg + base;
  const float* Vb = Vg + base;
  float*       Ob = Og + base;

  const float scale = 0.12753102f;  // (1/sqrt(128)) * log2(e)  -> log2-domain softmax
  const int wrow_lo = m0 + wv * 16;
  const int qg = wrow_lo + l15;     // this lane's q row

  // QK A-row permutation sigma0(m)=8*(m>>2)+(m&3) so S values land in PV B-frag order
  const int arow = ((l15 >> 2) << 3) + (l15 & 3);
  int krowb[4], kfx[4];
  #pragma unroll
  for (int c = 0; c < 4; ++c) {
    int kr = arow + (c & 1) * 4 + (c >> 1) * 32;
    krowb[c] = kr * 256;
    kfx[c] = ((kr & 3) | (((kr >> 3) & 1) << 2)) << 4;   // K swizzle for this row
  }

  // ---- Q B-frags (bf16, pre-scaled): lane -> q=l15, k=d=lhi*8+j ----
  short8 qf[4];
  {
    const float* qsrc = Qb + (size_t)qg * D_DIM + lhi * 8;
    #pragma unroll
    for (int kk = 0; kk < 4; ++kk) {
      f32x4 a = *(const f32x4*)(qsrc + kk * 32);
      f32x4 b = *(const f32x4*)(qsrc + kk * 32 + 4);
      u32x4 u;
      u[0] = pk2(a[0] * scale, a[1] * scale);
      u[1] = pk2(a[2] * scale, a[3] * scale);
      u[2] = pk2(b[0] * scale, b[1] * scale);
      u[3] = pk2(b[2] * scale, b[3] * scale);
      qf[kk] = __builtin_bit_cast(short8, u);
    }
  }

  // ---- staging helpers (512 threads) ----
  auto load_k = [&](int t, f32x4* kr) {
    const float* Kt = Kb + (size_t)t * BN * D_DIM;
    #pragma unroll
    for (int i = 0; i < 4; ++i) {
      int idx = i * 512 + tid;
      kr[i] = *(const f32x4*)(Kt + (size_t)(idx >> 5) * D_DIM + (idx & 31) * 4);
    }
  };
  auto store_k = [&](char* kb, const f32x4* kr) {
    #pragma unroll
    for (int i = 0; i < 4; ++i) {
      int idx = i * 512 + tid;
      int r = idx >> 5, c = idx & 31;
      int fk = ((r & 3) | (((r >> 3) & 1) << 2)) << 4;
      u32x2 w2; w2[0] = pk2(kr[i][0], kr[i][1]); w2[1] = pk2(kr[i][2], kr[i][3]);
      *(u32x2*)(kb + r * 256 + ((c * 8) ^ fk)) = w2;
    }
  };
  auto load_v = [&](int t, f32x4* vr) {
    const float* Vt = Vb + (size_t)t * BN * D_DIM;
    #pragma unroll
    for (int r = 0; r < 4; ++r)
      vr[r] = *(const f32x4*)(Vt + (size_t)(4 * vp + r) * D_DIM + vg4);
  };
  auto store_v = [&](char* vb, const f32x4* vr) {
    #pragma unroll
    for (int j = 0; j < 4; ++j) {
      int d = vg4 + j;
      u32x2 w2; w2[0] = pk2(vr[0][j], vr[1][j]); w2[1] = pk2(vr[2][j], vr[3][j]);
      *(u32x2*)(vb + ((d * 128 + vp * 8) ^ (((d >> 1) & 7) << 4))) = w2;
    }
  };

  const f32x4 fzero = {0.f, 0.f, 0.f, 0.f};
  f32x4 oacc[8];                    // O^T: lane holds its own q column
  #pragma unroll
  for (int i = 0; i < 8; ++i) oacc[i] = fzero;
  float m_run = -INFINITY, l_run = 0.f;

  const int ntiles = 2 * qt + 2;

  // ---- prologue: stage tile 0 ----
  {
    f32x4 st[4];
    load_k(0, st); store_k(Ksh, st);
    load_v(0, st); store_v(Vsh, st);
  }
  __syncthreads();

  int cur = 0;
  for (int t = 0; t < ntiles; ++t) {
    const int kv0 = t * BN;
    const bool pf = (t + 1 < ntiles);
    const bool comp = (kv0 <= wrow_lo + 15);   // wave-uniform causal skip

    f32x4 st[4];
    if (pf) load_k(t + 1, st);                 // issue early, hide under QK

    f32x4 sacc[4];
    if (comp) {
      // ---- S^T = K Q^T (log2 domain) ----
      const char* Kl = Ksh + cur * KBUF;
      __builtin_amdgcn_s_setprio(1);
      #pragma unroll
      for (int c = 0; c < 4; ++c) {
        sacc[c] = fzero;
        #pragma unroll
        for (int kk = 0; kk < 4; ++kk) {
          short8 kf = *(const short8*)(Kl + krowb[c] + ((kk * 64 + lhi * 16) ^ kfx[c]));
          sacc[c] = __builtin_amdgcn_mfma_f32_16x16x32_bf16(kf, qf[kk], sacc[c], 0, 0, 0);
        }
      }
      __builtin_amdgcn_s_setprio(0);
    }

    if (pf) store_k(Ksh + (cur ^ 1) * KBUF, st);   // K(t+1) -> alt buf
    if (pf) load_v(t + 1, st);                      // reuse regs; hides under softmax/PV

    if (comp) {
      // ---- causal mask: sacc[c][r] is kv = kv0 + 32(c>>1)+4(c&1)+8*lhi+r ----
      if (kv0 + BN - 1 > wrow_lo) {
        #pragma unroll
        for (int c = 0; c < 4; ++c) {
          const int kvb = kv0 + (c >> 1) * 32 + (c & 1) * 4 + lhi * 8;
          #pragma unroll
          for (int r = 0; r < 4; ++r)
            if (kvb + r > qg) sacc[c][r] = -INFINITY;
        }
      }

      // ---- online softmax (log2 domain), per-lane row + 2 shfls ----
      float mA[4];
      #pragma unroll
      for (int r = 0; r < 4; ++r)
        mA[r] = fmaxf(fmaxf(sacc[0][r], sacc[1][r]), fmaxf(sacc[2][r], sacc[3][r]));
      float mt = fmaxf(fmaxf(mA[0], mA[1]), fmaxf(mA[2], mA[3]));
      mt = fmaxf(mt, __shfl_xor(mt, 16));
      mt = fmaxf(mt, __shfl_xor(mt, 32));

      // defer-max (T13): skip O/l rescale when max growth bounded (P <= 2^11.5)
      if (!__all(mt <= m_run + 11.5f)) {
        const float m_new = fmaxf(m_run, mt);
        const float al = exp2f_hw(m_run - m_new);
        m_run = m_new;
        l_run *= al;
        #pragma unroll
        for (int dc = 0; dc < 8; ++dc)
          #pragma unroll
          for (int r = 0; r < 4; ++r) oacc[dc][r] *= al;
      }

      #pragma unroll
      for (int c = 0; c < 4; ++c)
        #pragma unroll
        for (int r = 0; r < 4; ++r)
          sacc[c][r] = exp2f_hw(sacc[c][r] - m_run);

      float sA[4];
      #pragma unroll
      for (int r = 0; r < 4; ++r)
        sA[r] = (sacc[0][r] + sacc[1][r]) + (sacc[2][r] + sacc[3][r]);
      float rs = (sA[0] + sA[1]) + (sA[2] + sA[3]);
      rs += __shfl_xor(rs, 16);
      rs += __shfl_xor(rs, 32);
      l_run += rs;

      // ---- P^T B-frags: pure in-lane packing (kv order matches by construction) ----
      short8 pfrag[2];
      #pragma unroll
      for (int w = 0; w < 2; ++w) {
        u32x4 u;
        u[0] = pk2(sacc[2 * w][0], sacc[2 * w][1]);
        u[1] = pk2(sacc[2 * w][2], sacc[2 * w][3]);
        u[2] = pk2(sacc[2 * w + 1][0], sacc[2 * w + 1][1]);
        u[3] = pk2(sacc[2 * w + 1][2], sacc[2 * w + 1][3]);
        pfrag[w] = __builtin_bit_cast(short8, u);
      }

      // ---- O^T += V^T P^T ----
      const char* Vl = Vsh + cur * VBUF;
      __builtin_amdgcn_s_setprio(1);
      #pragma unroll
      for (int dc = 0; dc < 8; ++dc) {
        const int drow = dc * 16 + l15;
        const int gx = ((drow >> 1) & 7) << 4;
        #pragma unroll
        for (int w = 0; w < 2; ++w) {
          short8 vf = *(const short8*)(Vl + drow * 128 + ((w * 64 + lhi * 16) ^ gx));
          oacc[dc] = __builtin_amdgcn_mfma_f32_16x16x32_bf16(vf, pfrag[w], oacc[dc], 0, 0, 0);
        }
      }
      __builtin_amdgcn_s_setprio(0);
    }

    if (pf) store_v(Vsh + (cur ^ 1) * VBUF, st);   // V(t+1) -> alt buf
    __syncthreads();
    cur ^= 1;
  }

  // ---- epilogue: O^T/l -> LDS transpose (2 phases of 64 rows) -> f32x4 stores ----
  const float invl = 1.0f / l_run;
  #pragma unroll
  for (int ph = 0; ph < 2; ++ph) {
    __syncthreads();
    if ((wv >> 2) == ph) {
      float* orow = &Osh[((wv & 3) * 16 + l15) * 132];
      #pragma unroll
      for (int dc = 0; dc < 8; ++dc)
        #pragma unroll
        for (int r = 0; r < 4; ++r)
          orow[dc * 16 + lhi * 4 + r] = oacc[dc][r] * invl;
    }
    __syncthreads();
    #pragma unroll
    for (int i = 0; i < 4; ++i) {
      int idx = i * 512 + tid;
      int row = idx >> 5, c4 = idx & 31;
      f32x4 v = *(const f32x4*)&Osh[row * 132 + c4 * 4];
      *(f32x4*)(Ob + (size_t)(m0 + ph * 64 + row) * D_DIM + c4 * 4) = v;
    }
  }
}

extern "C" void kernel_launch(void* const* d_in, const int* in_sizes, int n_in,
                              void* d_out, int out_size, void* d_ws, size_t ws_size,
                              hipStream_t stream) {
  const float* Q = (const float*)d_in[0];
  const float* K = (const float*)d_in[1];
  const float* V = (const float*)d_in[2];
  float* O = (float*)d_out;
  dim3 grid(32 /* B*H */, S_LEN / BM);
  dim3 block(512);
  fa_fwd_kernel<<<grid, block, 0, stream>>>(Q, K, V, O);
}